// Round 6
// baseline (1086.742 us; speedup 1.0000x reference)
//
#include <hip/hip_runtime.h>

#define NN 10000
#define EE 160000
#define DD 512
#define EDIM 128
#define LLAYERS 3
#define LN_EPS 1e-5f

typedef __attribute__((ext_vector_type(8))) short bf16x8;
typedef __attribute__((ext_vector_type(4))) float f32x4;

__device__ __forceinline__ unsigned short f2b(float f) {
    union { float f; unsigned u; } v; v.f = f;
    unsigned r = (v.u + 0x7fffu + ((v.u >> 16) & 1u)) >> 16;
    return (unsigned short)r;
}
__device__ __forceinline__ float b2f(unsigned short s) {
    union { unsigned u; float f; } v; v.u = ((unsigned)s) << 16;
    return v.f;
}

// ---------------- counting-sort building blocks ----------------
__global__ __launch_bounds__(256) void hist_kernel(
    const int* __restrict__ key, int* __restrict__ deg)
{
    int e = blockIdx.x * 256 + threadIdx.x;
    if (e < EE) atomicAdd(&deg[key[e]], 1);
}

// single block, 256 threads: exclusive scan of deg[0..NN) -> base, cursor
__global__ __launch_bounds__(256) void scan_kernel(
    const int* __restrict__ deg, int* __restrict__ base, int* __restrict__ cursor)
{
    __shared__ int sums[256];
    const int t = threadIdx.x;
    const int CH = 40;                       // 256*40 = 10240 >= NN
    int lo = t * CH;
    int hi = lo + CH; if (hi > NN) hi = NN;
    int s = 0;
    for (int i = lo; i < hi; i++) s += deg[i];
    sums[t] = s;
    __syncthreads();
    for (int off = 1; off < 256; off <<= 1) {
        int v = (t >= off) ? sums[t - off] : 0;
        __syncthreads();
        sums[t] += v;
        __syncthreads();
    }
    int run = (t == 0) ? 0 : sums[t - 1];
    for (int i = lo; i < hi; i++) {
        base[i] = run; cursor[i] = run;
        run += deg[i];
    }
}

// dst sort: only need inverse map orig_e -> dst-sorted position
__global__ __launch_bounds__(256) void scatter_inv_kernel(
    const int* __restrict__ dstv, int* __restrict__ cursor, int* __restrict__ invd)
{
    int e = blockIdx.x * 256 + threadIdx.x;
    if (e < EE) invd[e] = atomicAdd(&cursor[dstv[e]], 1);
}

// src sort: perm (pos -> orig e) and the sorted src values
__global__ __launch_bounds__(256) void scatter_src_kernel(
    const int* __restrict__ srcv, int* __restrict__ cursor,
    int* __restrict__ perm_s, int* __restrict__ ssrc_s)
{
    int e = blockIdx.x * 256 + threadIdx.x;
    if (e < EE) {
        int s = srcv[e];
        int pos = atomicAdd(&cursor[s], 1);
        perm_s[pos] = e;
        ssrc_s[pos] = s;
    }
}

// mtarget[p] = dst-sorted row for the edge processed at src-sorted pos p
__global__ __launch_bounds__(256) void map_kernel(
    const int* __restrict__ perm_s, const int* __restrict__ invd,
    int* __restrict__ mtarget)
{
    int p = blockIdx.x * 256 + threadIdx.x;
    if (p < EE) mtarget[p] = invd[perm_s[p]];
}

// ---------------- fp32 -> bf16 transpose (src[K][N] -> dst[N][K]) ----------------
__global__ __launch_bounds__(256) void transpose_bf16_kernel(
    const float* __restrict__ src, unsigned short* __restrict__ dst, int K, int N)
{
    __shared__ float t[32][33];
    const int x = threadIdx.x & 31;
    const int y = threadIdx.x >> 5;          // 0..7
    const int bn = blockIdx.x * 32;
    const int bk = blockIdx.y * 32;
    #pragma unroll
    for (int j = 0; j < 32; j += 8)
        t[y + j][x] = src[(size_t)(bk + y + j) * N + bn + x];
    __syncthreads();
    #pragma unroll
    for (int j = 0; j < 32; j += 8)
        dst[(size_t)(bn + y + j) * K + bk + x] = f2b(t[x][y + j]);
}

// ---------------- fp32 -> bf16 elementwise convert ----------------
__global__ __launch_bounds__(256) void cvt_bf16_kernel(
    const float* __restrict__ src, unsigned short* __restrict__ dst)
{
    int i = blockIdx.x * 256 + threadIdx.x;
    float4 v = ((const float4*)src)[i];
    uint2 o;
    o.x = (unsigned)f2b(v.x) | ((unsigned)f2b(v.y) << 16);
    o.y = (unsigned)f2b(v.z) | ((unsigned)f2b(v.w) << 16);
    ((uint2*)dst)[i] = o;
}

// ---------------- phase 1: message GEMM (src-sorted) ----------------
// m = relu(h[src] + ea@We + be) for a 128-col slab [c0, c0+128).
// Block: 64 src-sorted edges. 4 waves: wave w -> edge-half (w&1)*32,
// col-half (w>>1)*64. Writes bf16 messages to M[mtarget[pos]][c-c0]
// (dst-sorted rows; contiguous for the reducer). No atomics.
#define EP 136   // sA pitch: 128+8 bf16 -> 2-way bank alias (free)
__global__ __launch_bounds__(256) void msg_kernel(
    const unsigned short* __restrict__ h_bf,
    const float* __restrict__ edge_attr,
    const unsigned short* __restrict__ WeT,   // [512 n][128 k] bf16 (layer slice)
    const float* __restrict__ be,             // [512] fp32
    const int* __restrict__ perm_s,
    const int* __restrict__ ssrc_s,
    const int* __restrict__ mtarget,
    unsigned short* __restrict__ M,           // [E][128] bf16 slab
    int c0)
{
    __shared__ unsigned short sA[64 * EP];    // 17.4 KB
    __shared__ int sSrc[64];
    __shared__ int sRow[64];

    const int tid  = threadIdx.x;
    const int e0   = blockIdx.x * 64;
    const int w    = tid >> 6;
    const int lane = tid & 63;
    const int quad = lane >> 4;
    const int l16  = lane & 15;
    const int mh   = (w & 1) * 32;
    const int nsl  = (w >> 1) * 64;

    if (tid < 64) {
        sSrc[tid] = ssrc_s[e0 + tid];
        sRow[tid] = mtarget[e0 + tid];
    }
    // stage A: 64 edges x 16 segs of 8 fp32 -> 8 bf16 (perm_s gather)
    for (int i = tid; i < 64 * 16; i += 256) {
        int e = i >> 4, seg = i & 15;
        const float* p = edge_attr + (size_t)perm_s[e0 + e] * EDIM + seg * 8;
        float4 u = *(const float4*)p;
        float4 v = *(const float4*)(p + 4);
        uint4 o;
        o.x = (unsigned)f2b(u.x) | ((unsigned)f2b(u.y) << 16);
        o.y = (unsigned)f2b(u.z) | ((unsigned)f2b(u.w) << 16);
        o.z = (unsigned)f2b(v.x) | ((unsigned)f2b(v.y) << 16);
        o.w = (unsigned)f2b(v.z) | ((unsigned)f2b(v.w) << 16);
        *(uint4*)&sA[e * EP + seg * 8] = o;
    }
    __syncthreads();

    f32x4 acc[2][4];
    #pragma unroll
    for (int mr = 0; mr < 2; mr++)
        #pragma unroll
        for (int nb = 0; nb < 4; nb++)
            acc[mr][nb] = (f32x4){0.f, 0.f, 0.f, 0.f};

    #pragma unroll
    for (int ks = 0; ks < 4; ks++) {
        const int ko = ks * 32 + quad * 8;
        bf16x8 a0 = *(const bf16x8*)&sA[(mh + l16) * EP + ko];
        bf16x8 a1 = *(const bf16x8*)&sA[(mh + 16 + l16) * EP + ko];
        bf16x8 b[4];
        #pragma unroll
        for (int nb = 0; nb < 4; nb++)
            b[nb] = *(const bf16x8*)&WeT[(size_t)(c0 + nsl + nb * 16 + l16) * EDIM + ko];
        #pragma unroll
        for (int nb = 0; nb < 4; nb++) {
            acc[0][nb] = __builtin_amdgcn_mfma_f32_16x16x32_bf16(a0, b[nb], acc[0][nb], 0, 0, 0);
            acc[1][nb] = __builtin_amdgcn_mfma_f32_16x16x32_bf16(a1, b[nb], acc[1][nb], 0, 0, 0);
        }
    }

    // epilogue: C/D row = quad*4+reg -> 4 consecutive src-sorted edges
    #pragma unroll
    for (int mr = 0; mr < 2; mr++) {
        const int lb = mh + mr * 16 + quad * 4;
        const int s0 = sSrc[lb],     r0 = sRow[lb];
        const int s1 = sSrc[lb + 1], r1 = sRow[lb + 1];
        const int s2 = sSrc[lb + 2], r2 = sRow[lb + 2];
        const int s3 = sSrc[lb + 3], r3 = sRow[lb + 3];
        #pragma unroll
        for (int nb = 0; nb < 4; nb++) {
            const int c  = nsl + nb * 16 + l16;   // slab-local col
            const int gc = c0 + c;
            const float bias = be[gc];
            const f32x4 v = acc[mr][nb];
            M[(size_t)r0 * 128 + c] = f2b(fmaxf(v[0] + bias + b2f(h_bf[(size_t)s0 * DD + gc]), 0.f));
            M[(size_t)r1 * 128 + c] = f2b(fmaxf(v[1] + bias + b2f(h_bf[(size_t)s1 * DD + gc]), 0.f));
            M[(size_t)r2 * 128 + c] = f2b(fmaxf(v[2] + bias + b2f(h_bf[(size_t)s2 * DD + gc]), 0.f));
            M[(size_t)r3 * 128 + c] = f2b(fmaxf(v[3] + bias + b2f(h_bf[(size_t)s3 * DD + gc]), 0.f));
        }
    }
}

// ---------------- phase 2: CSR segment reduce (dst-sorted, streaming) ----------------
// agg[d][c0..c0+128) = sum of M rows base[d]..base[d]+deg[d]-1. No atomics.
// Block 256 = 16 groups of 16 lanes; group g handles dst blockIdx*16+g;
// lane reads 8 cols (bf16x8 = 16 B), accumulates fp32.
__global__ __launch_bounds__(256) void reduce_kernel(
    const unsigned short* __restrict__ M,     // [E][128]
    const int* __restrict__ base,
    const int* __restrict__ deg,
    float* __restrict__ agg,                  // [N][512] fp32
    int c0)
{
    const int tid = threadIdx.x;
    const int g   = tid >> 4;
    const int l16 = tid & 15;
    const int d   = blockIdx.x * 16 + g;
    if (d >= NN) return;

    const int b0 = base[d];
    const int n  = deg[d];

    float a0 = 0.f, a1 = 0.f, a2 = 0.f, a3 = 0.f;
    float a4 = 0.f, a5 = 0.f, a6 = 0.f, a7 = 0.f;

    const unsigned short* mp = M + (size_t)b0 * 128 + l16 * 8;
    int j = 0;
    for (; j + 2 <= n; j += 2) {
        uint4 v0 = *(const uint4*)(mp);
        uint4 v1 = *(const uint4*)(mp + 128);
        mp += 256;
        a0 += b2f((unsigned short)(v0.x & 0xffff)) + b2f((unsigned short)(v1.x & 0xffff));
        a1 += b2f((unsigned short)(v0.x >> 16))    + b2f((unsigned short)(v1.x >> 16));
        a2 += b2f((unsigned short)(v0.y & 0xffff)) + b2f((unsigned short)(v1.y & 0xffff));
        a3 += b2f((unsigned short)(v0.y >> 16))    + b2f((unsigned short)(v1.y >> 16));
        a4 += b2f((unsigned short)(v0.z & 0xffff)) + b2f((unsigned short)(v1.z & 0xffff));
        a5 += b2f((unsigned short)(v0.z >> 16))    + b2f((unsigned short)(v1.z >> 16));
        a6 += b2f((unsigned short)(v0.w & 0xffff)) + b2f((unsigned short)(v1.w & 0xffff));
        a7 += b2f((unsigned short)(v0.w >> 16))    + b2f((unsigned short)(v1.w >> 16));
    }
    if (j < n) {
        uint4 v0 = *(const uint4*)(mp);
        a0 += b2f((unsigned short)(v0.x & 0xffff));
        a1 += b2f((unsigned short)(v0.x >> 16));
        a2 += b2f((unsigned short)(v0.y & 0xffff));
        a3 += b2f((unsigned short)(v0.y >> 16));
        a4 += b2f((unsigned short)(v0.z & 0xffff));
        a5 += b2f((unsigned short)(v0.z >> 16));
        a6 += b2f((unsigned short)(v0.w & 0xffff));
        a7 += b2f((unsigned short)(v0.w >> 16));
    }

    float* ap = agg + (size_t)d * DD + c0 + l16 * 8;
    *(float4*)ap       = make_float4(a0, a1, a2, a3);
    *(float4*)(ap + 4) = make_float4(a4, a5, a6, a7);
}

// ---------------- node GEMM (MFMA bf16), optional fused (1+eps)*h + agg ----------------
#define GPITCH 136
template <bool FUSE, bool RELU, bool OUTBF>
__global__ __launch_bounds__(256) void mfma_gemm(
    const unsigned short* __restrict__ A,    // [M][512] bf16
    const float* __restrict__ aggp,          // [M][512] fp32 (FUSE only)
    const float* __restrict__ epsp,          // scalar (FUSE only)
    const unsigned short* __restrict__ WT,   // [512 n][512 k] bf16
    const float* __restrict__ bias,          // [512] fp32
    void* __restrict__ Cout, int M)
{
    __shared__ unsigned short sA[64 * GPITCH];    // 17.4 KB
    __shared__ unsigned short sB[128 * GPITCH];   // 34.8 KB

    const int tid  = threadIdx.x;
    const int m0   = blockIdx.x * 64;
    const int c0   = blockIdx.y * 128;
    const int w    = tid >> 6;
    const int lane = tid & 63;
    const int quad = lane >> 4;
    const int l16  = lane & 15;
    const int mh   = (w & 1) * 32;
    const int nsl  = (w >> 1) * 64;

    const float es = FUSE ? (1.0f + epsp[0]) : 0.0f;

    f32x4 acc[2][4];
    #pragma unroll
    for (int mr = 0; mr < 2; mr++)
        #pragma unroll
        for (int nb = 0; nb < 4; nb++)
            acc[mr][nb] = (f32x4){0.f, 0.f, 0.f, 0.f};

    for (int kc = 0; kc < DD; kc += 128) {
        __syncthreads();
        for (int i = tid; i < 64 * 16; i += 256) {   // A: 64 rows x 16 segs
            int r = i >> 4, seg = i & 15;
            int gm = m0 + r;
            uint4 v = make_uint4(0u, 0u, 0u, 0u);
            if (gm < M) {
                v = *(const uint4*)&A[(size_t)gm * DD + kc + seg * 8];
                if (FUSE) {
                    const float* ap = aggp + (size_t)gm * DD + kc + seg * 8;
                    float4 g0 = *(const float4*)ap;
                    float4 g1 = *(const float4*)(ap + 4);
                    uint4 o;
                    o.x = (unsigned)f2b(es * b2f((unsigned short)(v.x & 0xffff)) + g0.x)
                        | ((unsigned)f2b(es * b2f((unsigned short)(v.x >> 16)) + g0.y) << 16);
                    o.y = (unsigned)f2b(es * b2f((unsigned short)(v.y & 0xffff)) + g0.z)
                        | ((unsigned)f2b(es * b2f((unsigned short)(v.y >> 16)) + g0.w) << 16);
                    o.z = (unsigned)f2b(es * b2f((unsigned short)(v.z & 0xffff)) + g1.x)
                        | ((unsigned)f2b(es * b2f((unsigned short)(v.z >> 16)) + g1.y) << 16);
                    o.w = (unsigned)f2b(es * b2f((unsigned short)(v.w & 0xffff)) + g1.z)
                        | ((unsigned)f2b(es * b2f((unsigned short)(v.w >> 16)) + g1.w) << 16);
                    v = o;
                }
            }
            *(uint4*)&sA[r * GPITCH + seg * 8] = v;
        }
        for (int i = tid; i < 128 * 16; i += 256) {  // B: 128 rows x 16 segs
            int r = i >> 4, seg = i & 15;
            *(uint4*)&sB[r * GPITCH + seg * 8] =
                *(const uint4*)&WT[(size_t)(c0 + r) * DD + kc + seg * 8];
        }
        __syncthreads();
        #pragma unroll
        for (int ks = 0; ks < 4; ks++) {
            const int ko = ks * 32 + quad * 8;
            bf16x8 a0 = *(const bf16x8*)&sA[(mh + l16) * GPITCH + ko];
            bf16x8 a1 = *(const bf16x8*)&sA[(mh + 16 + l16) * GPITCH + ko];
            bf16x8 b[4];
            #pragma unroll
            for (int nb = 0; nb < 4; nb++)
                b[nb] = *(const bf16x8*)&sB[(nsl + nb * 16 + l16) * GPITCH + ko];
            #pragma unroll
            for (int nb = 0; nb < 4; nb++) {
                acc[0][nb] = __builtin_amdgcn_mfma_f32_16x16x32_bf16(a0, b[nb], acc[0][nb], 0, 0, 0);
                acc[1][nb] = __builtin_amdgcn_mfma_f32_16x16x32_bf16(a1, b[nb], acc[1][nb], 0, 0, 0);
            }
        }
    }

    #pragma unroll
    for (int mr = 0; mr < 2; mr++) {
        const int rbase = m0 + mh + mr * 16 + quad * 4;
        #pragma unroll
        for (int nb = 0; nb < 4; nb++) {
            const int c = c0 + nsl + nb * 16 + l16;
            const float bv = bias[c];
            const f32x4 v = acc[mr][nb];
            #pragma unroll
            for (int reg = 0; reg < 4; reg++) {
                int gm = rbase + reg;
                if (gm < M) {
                    float val = v[reg] + bv;
                    if (RELU) val = fmaxf(val, 0.f);
                    if (OUTBF) ((unsigned short*)Cout)[(size_t)gm * DD + c] = f2b(val);
                    else       ((float*)Cout)[(size_t)gm * DD + c] = val;
                }
            }
        }
    }
}

// ---------------- fused ReLU + LayerNorm (bf16 in/out, fp32 stats) ----------------
__global__ __launch_bounds__(256) void relu_ln_kernel(
    const unsigned short* __restrict__ g2,
    const float* __restrict__ gamma,
    const float* __restrict__ beta,
    unsigned short* __restrict__ hout)
{
    __shared__ float ss[4], ssq[4];
    const int row = blockIdx.x;
    const int tid = threadIdx.x;
    const unsigned short* gr = g2 + (size_t)row * DD;

    float v0 = fmaxf(b2f(gr[tid]), 0.f);
    float v1 = fmaxf(b2f(gr[tid + 256]), 0.f);
    float s  = v0 + v1;
    float sq = v0 * v0 + v1 * v1;
    #pragma unroll
    for (int off = 32; off > 0; off >>= 1) {
        s  += __shfl_down(s, off);
        sq += __shfl_down(sq, off);
    }
    const int wave = tid >> 6;
    const int lane = tid & 63;
    if (lane == 0) { ss[wave] = s; ssq[wave] = sq; }
    __syncthreads();
    if (tid == 0) {
        float S  = ss[0] + ss[1] + ss[2] + ss[3];
        float SQ = ssq[0] + ssq[1] + ssq[2] + ssq[3];
        float mu = S * (1.f / 512.f);
        float var = SQ * (1.f / 512.f) - mu * mu;
        ss[0]  = mu;
        ssq[0] = rsqrtf(var + LN_EPS);
    }
    __syncthreads();
    float mu = ss[0], rstd = ssq[0];
    hout[(size_t)row * DD + tid] =
        f2b((v0 - mu) * rstd * gamma[tid] + beta[tid]);
    hout[(size_t)row * DD + tid + 256] =
        f2b((v1 - mu) * rstd * gamma[tid + 256] + beta[tid + 256]);
}

extern "C" void kernel_launch(void* const* d_in, const int* in_sizes, int n_in,
                              void* d_out, int out_size, void* d_ws, size_t ws_size,
                              hipStream_t stream)
{
    (void)in_sizes; (void)n_in; (void)out_size; (void)ws_size;

    const float* x          = (const float*)d_in[0];
    const int*   edge_index = (const int*)d_in[1];   // int32 per harness contract
    const float* edge_attr  = (const float*)d_in[2];
    const float* We         = (const float*)d_in[3];
    const float* be         = (const float*)d_in[4];
    const float* eps        = (const float*)d_in[5];
    const float* W1         = (const float*)d_in[6];
    const float* b1         = (const float*)d_in[7];
    const float* W2         = (const float*)d_in[8];
    const float* b2         = (const float*)d_in[9];
    const float* gamma      = (const float*)d_in[10];
    const float* beta       = (const float*)d_in[11];
    const float* Wf         = (const float*)d_in[12];
    const float* bf         = (const float*)d_in[13];

    // ---- workspace layout (~79 MB) ----
    float*          agg  = (float*)d_ws;                           // [N*512] f32
    unsigned short* t2   = (unsigned short*)agg;                   // alias (gemm2 out)
    unsigned short* h_bf = (unsigned short*)(agg + (size_t)NN*DD); // [N*512]
    unsigned short* Mbuf = h_bf + (size_t)NN * DD;                 // [E*128] bf16 slab
    unsigned short* t1   = Mbuf;                                   // alias (gemm1 out; M dead then)
    unsigned short* WeT  = Mbuf + (size_t)EE * EDIM;               // [3][512][128]
    unsigned short* W1T  = WeT + (size_t)3 * DD * EDIM;            // [3][512][512]
    unsigned short* W2T  = W1T + (size_t)3 * DD * DD;
    unsigned short* WfT  = W2T + (size_t)3 * DD * DD;              // [512][512]
    int* deg_d    = (int*)(WfT + (size_t)DD * DD);  // [N]
    int* base_d   = deg_d + NN;
    int* cursor_d = base_d + NN;
    int* deg_s    = cursor_d + NN;
    int* base_s   = deg_s + NN;
    int* cursor_s = base_s + NN;
    int* invd     = cursor_s + NN;                  // [E]
    int* perm_s   = invd + EE;                      // [E]
    int* ssrc_s   = perm_s + EE;                    // [E]
    int* mtarget  = ssrc_s + EE;                    // [E]

    const int* srcv = edge_index;
    const int* dstv = edge_index + EE;

    // ---- prepass (once per launch) ----
    hipMemsetAsync(deg_d, 0, NN * sizeof(int), stream);
    hipMemsetAsync(deg_s, 0, NN * sizeof(int), stream);
    hist_kernel<<<dim3((EE + 255) / 256), 256, 0, stream>>>(dstv, deg_d);
    hist_kernel<<<dim3((EE + 255) / 256), 256, 0, stream>>>(srcv, deg_s);
    scan_kernel<<<dim3(1), 256, 0, stream>>>(deg_d, base_d, cursor_d);
    scan_kernel<<<dim3(1), 256, 0, stream>>>(deg_s, base_s, cursor_s);
    scatter_inv_kernel<<<dim3((EE + 255) / 256), 256, 0, stream>>>(dstv, cursor_d, invd);
    scatter_src_kernel<<<dim3((EE + 255) / 256), 256, 0, stream>>>(srcv, cursor_s, perm_s, ssrc_s);
    map_kernel<<<dim3((EE + 255) / 256), 256, 0, stream>>>(perm_s, invd, mtarget);

    cvt_bf16_kernel<<<dim3(NN * DD / 4 / 256), 256, 0, stream>>>(x, h_bf);
    for (int l = 0; l < LLAYERS; l++) {
        transpose_bf16_kernel<<<dim3(DD / 32, EDIM / 32), 256, 0, stream>>>(
            We + (size_t)l * EDIM * DD, WeT + (size_t)l * DD * EDIM, EDIM, DD);
        transpose_bf16_kernel<<<dim3(DD / 32, DD / 32), 256, 0, stream>>>(
            W1 + (size_t)l * DD * DD, W1T + (size_t)l * DD * DD, DD, DD);
        transpose_bf16_kernel<<<dim3(DD / 32, DD / 32), 256, 0, stream>>>(
            W2 + (size_t)l * DD * DD, W2T + (size_t)l * DD * DD, DD, DD);
    }
    transpose_bf16_kernel<<<dim3(DD / 32, DD / 32), 256, 0, stream>>>(Wf, WfT, DD, DD);

    dim3 gblk(256), ggrid((NN + 63) / 64, DD / 128);

    for (int l = 0; l < LLAYERS; l++) {
        // edge pipeline: per 128-col slab, msg GEMM then CSR reduce (no atomics)
        for (int s = 0; s < 4; s++) {
            msg_kernel<<<dim3(EE / 64), 256, 0, stream>>>(
                h_bf, edge_attr, WeT + (size_t)l * DD * EDIM, be + (size_t)l * DD,
                perm_s, ssrc_s, mtarget, Mbuf, s * 128);
            reduce_kernel<<<dim3((NN + 15) / 16), 256, 0, stream>>>(
                Mbuf, base_d, deg_d, agg, s * 128);
        }
        // gemm1: A' = (1+eps)*h + agg (fused), relu, -> t1 (bf16)
        mfma_gemm<true, true, true><<<ggrid, gblk, 0, stream>>>(
            h_bf, agg, eps + l, W1T + (size_t)l * DD * DD, b1 + (size_t)l * DD, t1, NN);
        // gemm2: t1 @ W2 -> t2 (bf16, reuses agg storage)
        mfma_gemm<false, false, true><<<ggrid, gblk, 0, stream>>>(
            t1, nullptr, nullptr, W2T + (size_t)l * DD * DD, b2 + (size_t)l * DD, t2, NN);
        relu_ln_kernel<<<dim3(NN), 256, 0, stream>>>(
            t2, gamma + (size_t)l * DD, beta + (size_t)l * DD, h_bf);
    }
    mfma_gemm<false, false, false><<<ggrid, gblk, 0, stream>>>(
        h_bf, nullptr, nullptr, WfT, bf, d_out, NN);
}